// Round 1
// baseline (1427.524 us; speedup 1.0000x reference)
//
#include <hip/hip_runtime.h>
#include <math.h>

// ---------------- problem constants ----------------
#define BB     64          // batch
#define DD     4096        // model dim
#define NQ     32          // query heads
#define KVH    8           // kv heads
#define GG     4           // NQ / KVH
#define HD     128         // head dim
#define PAGES  64          // pages per seq
#define PSIZE  16          // slots per page
#define NSLOTS 65536
#define CACHE1 67108864UL  // floats per cache side (NSLOTS*KVH*HD)
#define CACHE2 134217728UL // floats both sides
#define ATTN_ELEMS (BB*DD) // 262144 floats
#define K_MASK_F (-2.3819763e+38f)
#define SM_SCALE 0.08838834764831845f

// ws layout (floats):
#define WS_QKV 0UL          // B*48*128 = 393216  (projection accumulators, must be zeroed)
#define WS_QR  393216UL     // B*NQ*HD = 262144   (q after rope)
#define WS_AT  655360UL     // B*NQ*HD = 262144   (attention out, pre o-proj)

// ---------------- K1: cache copy + zero scratch/out regions ----------------
__global__ __launch_bounds__(256) void k1_copy(const float4* __restrict__ cache,
                                               float4* __restrict__ out,
                                               float4* __restrict__ ws) {
    const long nc = CACHE2 / 4;       // 33554432
    const long na = ATTN_ELEMS / 4;   // 65536
    const long nw = 393216 / 4;       // 98304
    const long total = nc + na + nw;
    const long stride = (long)gridDim.x * blockDim.x;
    for (long i = (long)blockIdx.x * blockDim.x + threadIdx.x; i < total; i += stride) {
        if (i < nc) {
            out[i] = cache[i];
        } else if (i < nc + na) {
            out[i] = float4{0.f, 0.f, 0.f, 0.f};     // attn-output region directly follows cache
        } else {
            ws[i - nc - na] = float4{0.f, 0.f, 0.f, 0.f};
        }
    }
}

// ---------------- K2: QKV projection  X(64x4096) @ W(4096x48*128) ----------------
// grid (8 jt, 48 u), 256 threads. Thread: dc = t&31 covers d = dc + dd*32 (4 cols),
// bh = t>>5 covers b = bh*8 + i (8 batches). atomicAdd partial sums into ws_qkv.
__global__ __launch_bounds__(256) void k2_qkv(const float* __restrict__ x,
                                              const float* __restrict__ q_w,
                                              const float* __restrict__ kv_w,
                                              float* __restrict__ ws_qkv) {
    const int jt = blockIdx.x;  // 0..7  (512 j's each)
    const int u  = blockIdx.y;  // 0..47 (32 q heads, 8 k heads, 8 v heads)
    const float* w = (u < 32) ? (q_w + (size_t)u * DD * HD)
                              : (kv_w + (size_t)(u - 32) * DD * HD);
    const int t  = threadIdx.x;
    const int dc = t & 31;
    const int bh = t >> 5;      // 0..7

    __shared__ float lx[64][128];
    float acc[8][4];
    #pragma unroll
    for (int i = 0; i < 8; ++i)
        #pragma unroll
        for (int d = 0; d < 4; ++d) acc[i][d] = 0.f;

    for (int chunk = 0; chunk < 4; ++chunk) {
        const int jc = jt * 512 + chunk * 128;
        __syncthreads();
        // stage x[0..64][jc..jc+128) into LDS (float4 coalesced)
        const float4* x4 = reinterpret_cast<const float4*>(x);
        float4* lx4 = reinterpret_cast<float4*>(&lx[0][0]);
        for (int f = t; f < 64 * 32; f += 256) {
            int i = f >> 5, j4 = f & 31;
            lx4[i * 32 + j4] = x4[(size_t)i * (DD / 4) + (jc / 4) + j4];
        }
        __syncthreads();

        const float* wp = w + (size_t)jc * HD + dc;
        for (int jj4 = 0; jj4 < 32; ++jj4) {
            float wv[4][4];  // [jq][dcol]
            #pragma unroll
            for (int q = 0; q < 4; ++q)
                #pragma unroll
                for (int d = 0; d < 4; ++d)
                    wv[q][d] = wp[(size_t)(jj4 * 4 + q) * HD + d * 32];
            #pragma unroll
            for (int i = 0; i < 8; ++i) {
                float4 xv = *reinterpret_cast<const float4*>(&lx[bh * 8 + i][jj4 * 4]);
                #pragma unroll
                for (int d = 0; d < 4; ++d)
                    acc[i][d] += xv.x * wv[0][d] + xv.y * wv[1][d] +
                                 xv.z * wv[2][d] + xv.w * wv[3][d];
            }
        }
    }
    #pragma unroll
    for (int i = 0; i < 8; ++i) {
        int b = bh * 8 + i;
        #pragma unroll
        for (int d = 0; d < 4; ++d)
            atomicAdd(&ws_qkv[((size_t)b * 48 + u) * HD + dc + d * 32], acc[i][d]);
    }
}

// ---------------- K3: RoPE q & k, scatter new k/v into out-cache ----------------
__global__ __launch_bounds__(256) void k3_rope(const float* __restrict__ ws_qkv,
                                               float* __restrict__ ws_qr,
                                               float* __restrict__ outc,
                                               const int* __restrict__ segpos,
                                               const int* __restrict__ slotmap) {
    const int b = blockIdx.x;
    const int t = threadIdx.x;
    const float pos = (float)segpos[b];
    const int slot = slotmap[b];
    const float* qk = ws_qkv + (size_t)b * 48 * 128;

    // q heads: 32 heads x 64 rotation pairs
    for (int f = t; f < NQ * 64; f += 256) {
        int n = f >> 6, i = f & 63;
        float ts = __powf(10000.f, (float)i * (1.f / 64.f));
        float ang = pos / ts;
        float s, c;
        sincosf(ang, &s, &c);
        float a = qk[n * 128 + i], d2 = qk[n * 128 + i + 64];
        ws_qr[((size_t)b * NQ + n) * HD + i]      = a * c - d2 * s;
        ws_qr[((size_t)b * NQ + n) * HD + i + 64] = d2 * c + a * s;
    }
    // k heads: rope + scatter into K cache
    for (int f = t; f < KVH * 64; f += 256) {
        int kh = f >> 6, i = f & 63;
        float ts = __powf(10000.f, (float)i * (1.f / 64.f));
        float ang = pos / ts;
        float s, c;
        sincosf(ang, &s, &c);
        float a = qk[(32 + kh) * 128 + i], d2 = qk[(32 + kh) * 128 + i + 64];
        outc[((size_t)slot * KVH + kh) * HD + i]      = a * c - d2 * s;
        outc[((size_t)slot * KVH + kh) * HD + i + 64] = d2 * c + a * s;
    }
    // v heads: plain scatter into V cache
    for (int f = t; f < KVH * HD; f += 256) {
        int kh = f >> 7, h = f & 127;
        outc[CACHE1 + ((size_t)slot * KVH + kh) * HD + h] = qk[(40 + kh) * 128 + h];
    }
}

// ---------------- K4: paged attention decode ----------------
// grid (8 kv-heads, 64 batch), 256 threads.
__global__ __launch_bounds__(256) void k4_attn(const float* __restrict__ outc,
                                               const float* __restrict__ ws,
                                               float* __restrict__ ws_at,
                                               const int* __restrict__ bt,
                                               const int* __restrict__ ctx) {
    const int k = blockIdx.x;   // kv head
    const int b = blockIdx.y;   // batch
    const int t = threadIdx.x;
    const int Lb = ctx[b];
    const int npages = (Lb + 15) >> 4;
    const int Lpad = npages << 4;

    __shared__ float logit[GG][PAGES * PSIZE];  // 16 KB (holds e after phase2)
    __shared__ float accw[4][GG][HD];           // 8 KB
    __shared__ float inv_s[GG];

    const float* qr = ws + WS_QR + ((size_t)b * NQ + k * GG) * HD;
    const int sub = t & 15, pin = t >> 4;

    // preload this thread's q fragment (8 floats per g), pre-scaled
    float qf[GG][8];
    #pragma unroll
    for (int g = 0; g < GG; ++g) {
        const float4* qp = reinterpret_cast<const float4*>(qr + g * HD + sub * 8);
        float4 q0 = qp[0], q1 = qp[1];
        qf[g][0] = q0.x * SM_SCALE; qf[g][1] = q0.y * SM_SCALE;
        qf[g][2] = q0.z * SM_SCALE; qf[g][3] = q0.w * SM_SCALE;
        qf[g][4] = q1.x * SM_SCALE; qf[g][5] = q1.y * SM_SCALE;
        qf[g][6] = q1.z * SM_SCALE; qf[g][7] = q1.w * SM_SCALE;
    }

    const float* kbase = outc;
    const float* vbase = outc + CACHE1;
    const int* btb = bt + b * PAGES;

    // phase 1: logits. 16 positions/iter, 16 threads per position.
    for (int page = 0; page < npages; ++page) {
        int slot = btb[page] * PSIZE + pin;
        const float4* kp = reinterpret_cast<const float4*>(
            kbase + ((size_t)slot * KVH + k) * HD + sub * 8);
        float4 k0 = kp[0], k1 = kp[1];
        float pr[GG];
        #pragma unroll
        for (int g = 0; g < GG; ++g) {
            float p = qf[g][0] * k0.x + qf[g][1] * k0.y + qf[g][2] * k0.z + qf[g][3] * k0.w +
                      qf[g][4] * k1.x + qf[g][5] * k1.y + qf[g][6] * k1.z + qf[g][7] * k1.w;
            #pragma unroll
            for (int m = 1; m < 16; m <<= 1) p += __shfl_xor(p, m);
            pr[g] = p;
        }
        if (sub == 0) {
            int gp = page * PSIZE + pin;
            bool valid = gp < Lb;
            #pragma unroll
            for (int g = 0; g < GG; ++g) logit[g][gp] = valid ? pr[g] : K_MASK_F;
        }
    }
    __syncthreads();

    // phase 2: softmax per g (wave w handles g=w)
    const int w = t >> 6, lane = t & 63;
    {
        float m = -INFINITY;
        for (int p = lane; p < Lpad; p += 64) m = fmaxf(m, logit[w][p]);
        #pragma unroll
        for (int s = 1; s < 64; s <<= 1) m = fmaxf(m, __shfl_xor(m, s));
        float sum = 0.f;
        for (int p = lane; p < Lpad; p += 64) {
            float e = __expf(logit[w][p] - m);
            logit[w][p] = e;
            sum += e;
        }
        #pragma unroll
        for (int s = 1; s < 64; s <<= 1) sum += __shfl_xor(sum, s);
        if (lane == 0) inv_s[w] = 1.f / sum;
    }
    __syncthreads();

    // phase 3: O = P V. wave w handles positions p = w, w+4, ...
    float2 acc[GG];
    #pragma unroll
    for (int g = 0; g < GG; ++g) acc[g] = float2{0.f, 0.f};
    for (int p = w; p < Lpad; p += 4) {
        int slot = btb[p >> 4] * PSIZE + (p & 15);
        const float2* vp = reinterpret_cast<const float2*>(
            vbase + ((size_t)slot * KVH + k) * HD) + lane;
        float2 v = *vp;
        #pragma unroll
        for (int g = 0; g < GG; ++g) {
            float e = logit[g][p];
            acc[g].x += e * v.x;
            acc[g].y += e * v.y;
        }
    }
    #pragma unroll
    for (int g = 0; g < GG; ++g) {
        accw[w][g][2 * lane]     = acc[g].x;
        accw[w][g][2 * lane + 1] = acc[g].y;
    }
    __syncthreads();

    for (int f = t; f < GG * HD; f += 256) {
        int g = f >> 7, h = f & 127;
        float o = (accw[0][g][h] + accw[1][g][h] + accw[2][g][h] + accw[3][g][h]) * inv_s[g];
        ws_at[((size_t)b * NQ + k * GG + g) * HD + h] = o;
    }
}

// ---------------- K5: output projection  A(64x4096) @ o_w(4096x4096) ----------------
// grid (8 jt, 32 dt), 256 threads, atomicAdd partials into d_out attn region.
__global__ __launch_bounds__(256) void k5_oproj(const float* __restrict__ ws,
                                                const float* __restrict__ o_w,
                                                float* __restrict__ out) {
    const int jt = blockIdx.x;  // 0..7
    const int dt = blockIdx.y;  // 0..31
    const int t  = threadIdx.x;
    const int dc = t & 31;
    const int bh = t >> 5;      // 0..7
    const int d0 = dt * 128;

    __shared__ float lx[64][128];
    float acc[8][4];
    #pragma unroll
    for (int i = 0; i < 8; ++i)
        #pragma unroll
        for (int d = 0; d < 4; ++d) acc[i][d] = 0.f;

    const float* xa = ws + WS_AT;
    for (int chunk = 0; chunk < 4; ++chunk) {
        const int jc = jt * 512 + chunk * 128;
        __syncthreads();
        const float4* x4 = reinterpret_cast<const float4*>(xa);
        float4* lx4 = reinterpret_cast<float4*>(&lx[0][0]);
        for (int f = t; f < 64 * 32; f += 256) {
            int i = f >> 5, j4 = f & 31;
            lx4[i * 32 + j4] = x4[(size_t)i * (DD / 4) + (jc / 4) + j4];
        }
        __syncthreads();

        const float* wp = o_w + (size_t)jc * DD + d0 + dc;
        for (int jj4 = 0; jj4 < 32; ++jj4) {
            float wv[4][4];
            #pragma unroll
            for (int q = 0; q < 4; ++q)
                #pragma unroll
                for (int d = 0; d < 4; ++d)
                    wv[q][d] = wp[(size_t)(jj4 * 4 + q) * DD + d * 32];
            #pragma unroll
            for (int i = 0; i < 8; ++i) {
                float4 xv = *reinterpret_cast<const float4*>(&lx[bh * 8 + i][jj4 * 4]);
                #pragma unroll
                for (int d = 0; d < 4; ++d)
                    acc[i][d] += xv.x * wv[0][d] + xv.y * wv[1][d] +
                                 xv.z * wv[2][d] + xv.w * wv[3][d];
            }
        }
    }
    #pragma unroll
    for (int i = 0; i < 8; ++i) {
        int b = bh * 8 + i;
        #pragma unroll
        for (int d = 0; d < 4; ++d)
            atomicAdd(&out[CACHE2 + (size_t)b * DD + d0 + dc + d * 32], acc[i][d]);
    }
}

// ---------------- launch ----------------
extern "C" void kernel_launch(void* const* d_in, const int* in_sizes, int n_in,
                              void* d_out, int out_size, void* d_ws, size_t ws_size,
                              hipStream_t stream) {
    const float* x        = (const float*)d_in[0];
    const int*   segpos   = (const int*)d_in[1];
    const int*   slotmap  = (const int*)d_in[2];
    const int*   bt       = (const int*)d_in[3];
    const int*   ctx      = (const int*)d_in[4];
    const float* cache    = (const float*)d_in[5];
    const float* q_w      = (const float*)d_in[6];
    const float* kv_w     = (const float*)d_in[7];
    const float* o_w      = (const float*)d_in[8];
    float* out = (float*)d_out;
    float* ws  = (float*)d_ws;

    // K1: copy 512 MB cache -> out, zero attn-out region + ws accumulators
    k1_copy<<<4096, 256, 0, stream>>>((const float4*)cache, (float4*)out, (float4*)ws);
    // K2: QKV projection partials into ws_qkv
    k2_qkv<<<dim3(8, 48), 256, 0, stream>>>(x, q_w, kv_w, ws + WS_QKV);
    // K3: rope q (-> ws_qr), rope k + scatter k/v into out cache
    k3_rope<<<BB, 256, 0, stream>>>(ws + WS_QKV, ws + WS_QR, out, segpos, slotmap);
    // K4: paged attention -> ws_at
    k4_attn<<<dim3(KVH, BB), 256, 0, stream>>>(out, ws, ws + WS_AT, bt, ctx);
    // K5: output projection -> out[CACHE2 ...]
    k5_oproj<<<dim3(8, 32), 256, 0, stream>>>(ws, o_w, out);
}